// Round 13
// baseline (340.282 us; speedup 1.0000x reference)
//
#include <hip/hip_runtime.h>
#include <hip/hip_bf16.h>
#include <hip/hip_cooperative_groups.h>

namespace cg = cooperative_groups;

#define H 16
#define F_IN 58
#define NPB 16     // nodes per block in t0 (256 threads / 16 lanes)
#define SCH 4160   // max edges per stage chunk (LDS sort capacity)
#define ECAP 4096  // LDS edge-cache capacity in fallback agg
#define WECAP 2560 // per-window LDS edge cache in coop agg (Poisson(2048)+11 sigma)
#define MAXW 2     // windows per block in coop agg (fully unrolled)

static inline size_t align256(size_t x) { return (x + 255) & ~(size_t)255; }

__device__ inline float bfu2f(unsigned short u) {
    return __uint_as_float(((unsigned)u) << 16);
}

// ---------- dtype detection: int64 vs int32 edge_index ----------
__global__ void detect_kernel(const int* eidx32, int* flag) {
    __shared__ int any;
    if (threadIdx.x == 0) any = 0;
    __syncthreads();
    int nz = 0;
    for (int j = threadIdx.x; j < 1024; j += 256)
        nz |= (eidx32[2 * j + 1] != 0);
    if (nz) atomicOr(&any, 1);
    __syncthreads();
    if (threadIdx.x == 0) *flag = (any == 0) ? 1 : 0;  // all-zero odd words -> int64
}

__device__ inline int load_idx(const void* eidx, long i, int is64) {
    if (is64) return (int)((const long long*)eidx)[i];
    return ((const int*)eidx)[i];
}

// ---------- bucket counts (391 bins of 256 nodes), vectorized dst reads ----------
__global__ void bcount_kernel(const void* eidx, int E, const int* flag64,
                              int n, int* bucketcnt) {
    __shared__ int hist[512];
    int is64 = *flag64;
    int B = (n + 255) >> 8;
    int tid = threadIdx.x;
    for (int j = tid; j < B; j += 256) hist[j] = 0;
    __syncthreads();
    int stride = gridDim.x * blockDim.x;
    int gid = blockIdx.x * blockDim.x + tid;
    if (is64) {
        const longlong2* d2 = (const longlong2*)((const long long*)eidx + E);
        int half = E >> 1;
        for (int i = gid; i < half; i += stride) {
            longlong2 q = d2[i];
            atomicAdd(&hist[((int)q.x) >> 8], 1);
            atomicAdd(&hist[((int)q.y) >> 8], 1);
        }
        if (gid == 0 && (E & 1)) {
            int d = (int)((const long long*)eidx)[2 * (long)E - 1];
            atomicAdd(&hist[d >> 8], 1);
        }
    } else {
        const int4* d4 = (const int4*)((const int*)eidx + E);
        int quarter = E >> 2;
        for (int i = gid; i < quarter; i += stride) {
            int4 q = d4[i];
            atomicAdd(&hist[q.x >> 8], 1);
            atomicAdd(&hist[q.y >> 8], 1);
            atomicAdd(&hist[q.z >> 8], 1);
            atomicAdd(&hist[q.w >> 8], 1);
        }
        for (int i = (quarter << 2) + gid; i < E; i += stride) {
            int d = ((const int*)eidx)[(long)E + i];
            atomicAdd(&hist[d >> 8], 1);
        }
    }
    __syncthreads();
    for (int j = tid; j < B; j += 256)
        if (hist[j]) atomicAdd(&bucketcnt[j], hist[j]);
}

// ---------- exclusive scan of bucket counts (single block, B <= 512) ----------
__global__ void bscan_kernel(const int* bucketcnt, int B, int E,
                             int* gcur, int* bucketbase) {
    __shared__ int tmp[512];
    int tid = threadIdx.x;
    int val = (tid < B) ? bucketcnt[tid] : 0;
    tmp[tid] = val;
    __syncthreads();
    for (int off = 1; off < 512; off <<= 1) {
        int t = (tid >= off) ? tmp[tid - off] : 0;
        __syncthreads();
        tmp[tid] += t;
        __syncthreads();
    }
    if (tid < B) {
        int ex = tmp[tid] - val;
        gcur[tid] = ex;
        bucketbase[tid] = ex;
    }
    if (tid == 0) bucketbase[B] = E;
}

// ---------- stage: LDS counting-sort each chunk by bucket, write coalesced runs ----------
__global__ void stage_kernel(const void* eidx, int E, const int* flag64,
                             int n, int* gcur, unsigned* staging) {
    __shared__ unsigned sorted[SCH];
    __shared__ unsigned short sbuck[SCH];
    __shared__ int hist[512];
    __shared__ int hbase[512];
    __shared__ int lofs[512];
    __shared__ int cursor[512];
    __shared__ int ps[256];

    int is64 = *flag64;
    int tid = threadIdx.x;
    int chunk = (E + gridDim.x - 1) / gridDim.x;
    int s0 = blockIdx.x * chunk;
    int s1 = min(E, s0 + chunk);
    int c = s1 - s0;
    if (c <= 0) return;

    for (int j = tid; j < 512; j += 256) { hist[j] = 0; cursor[j] = 0; }
    __syncthreads();

    // pass A: per-chunk bucket histogram (vectorized dst reads)
    if (is64) {
        const longlong2* dp = (const longlong2*)((const long long*)eidx + E + s0);
        int m = c >> 1;
        for (int i = tid; i < m; i += 256) {
            longlong2 q = dp[i];
            atomicAdd(&hist[((int)q.x) >> 8], 1);
            atomicAdd(&hist[((int)q.y) >> 8], 1);
        }
        if (tid == 0 && (c & 1)) {
            int d = (int)((const long long*)eidx)[(long)E + s1 - 1];
            atomicAdd(&hist[d >> 8], 1);
        }
    } else {
        const int2* dp = (const int2*)((const int*)eidx + E + s0);
        int m = c >> 1;
        for (int i = tid; i < m; i += 256) {
            int2 q = dp[i];
            atomicAdd(&hist[q.x >> 8], 1);
            atomicAdd(&hist[q.y >> 8], 1);
        }
        if (tid == 0 && (c & 1)) {
            int d = ((const int*)eidx)[(long)E + s1 - 1];
            atomicAdd(&hist[d >> 8], 1);
        }
    }
    __syncthreads();

    // pass B: reserve global run per bucket
    for (int j = tid; j < 512; j += 256) {
        int cc = hist[j];
        hbase[j] = cc ? atomicAdd(&gcur[j], cc) : 0;
    }

    // pass C: exclusive scan of hist -> lofs (512 bins, 256 threads)
    int a0 = hist[2 * tid], a1 = hist[2 * tid + 1];
    ps[tid] = a0 + a1;
    __syncthreads();
    for (int off = 1; off < 256; off <<= 1) {
        int t = (tid >= off) ? ps[tid - off] : 0;
        __syncthreads();
        ps[tid] += t;
        __syncthreads();
    }
    int ex = ps[tid] - (a0 + a1);
    lofs[2 * tid] = ex;
    lofs[2 * tid + 1] = ex + a0;
    __syncthreads();

    // pass D: scatter into LDS in bucket-sorted order (vectorized src+dst reads)
    if (is64) {
        const longlong2* sp = (const longlong2*)((const long long*)eidx + s0);
        const longlong2* dp = (const longlong2*)((const long long*)eidx + E + s0);
        int m = c >> 1;
        for (int i = tid; i < m; i += 256) {
            longlong2 qs = sp[i];
            longlong2 qd = dp[i];
            int s = (int)qs.x, d = (int)qd.x;
            int b = d >> 8;
            int loc = lofs[b] + atomicAdd(&cursor[b], 1);
            sorted[loc] = (unsigned)s | ((unsigned)(d & 255) << 17);
            sbuck[loc] = (unsigned short)b;
            s = (int)qs.y; d = (int)qd.y;
            b = d >> 8;
            loc = lofs[b] + atomicAdd(&cursor[b], 1);
            sorted[loc] = (unsigned)s | ((unsigned)(d & 255) << 17);
            sbuck[loc] = (unsigned short)b;
        }
        if (tid == 0 && (c & 1)) {
            int s = (int)((const long long*)eidx)[(long)s1 - 1];
            int d = (int)((const long long*)eidx)[(long)E + s1 - 1];
            int b = d >> 8;
            int loc = lofs[b] + atomicAdd(&cursor[b], 1);
            sorted[loc] = (unsigned)s | ((unsigned)(d & 255) << 17);
            sbuck[loc] = (unsigned short)b;
        }
    } else {
        const int2* sp = (const int2*)((const int*)eidx + s0);
        const int2* dp = (const int2*)((const int*)eidx + E + s0);
        int m = c >> 1;
        for (int i = tid; i < m; i += 256) {
            int2 qs = sp[i];
            int2 qd = dp[i];
            int b = qd.x >> 8;
            int loc = lofs[b] + atomicAdd(&cursor[b], 1);
            sorted[loc] = (unsigned)qs.x | ((unsigned)(qd.x & 255) << 17);
            sbuck[loc] = (unsigned short)b;
            b = qd.y >> 8;
            loc = lofs[b] + atomicAdd(&cursor[b], 1);
            sorted[loc] = (unsigned)qs.y | ((unsigned)(qd.y & 255) << 17);
            sbuck[loc] = (unsigned short)b;
        }
        if (tid == 0 && (c & 1)) {
            int s = ((const int*)eidx)[(long)s1 - 1];
            int d = ((const int*)eidx)[(long)E + s1 - 1];
            int b = d >> 8;
            int loc = lofs[b] + atomicAdd(&cursor[b], 1);
            sorted[loc] = (unsigned)s | ((unsigned)(d & 255) << 17);
            sbuck[loc] = (unsigned short)b;
        }
    }
    __syncthreads();

    // pass E: linear LDS read, coalesced run writes to global
    for (int i = tid; i < c; i += 256) {
        int b = sbuck[i];
        staging[hbase[b] + (i - lofs[b])] = sorted[i];
    }
}

// ---------- per-bucket local hist + scan -> rowstart/dinv, node-sorted ed ----------
__global__ void fine_kernel(const unsigned* __restrict__ staging,
                            const int* __restrict__ bucketbase, int n, int E,
                            int* __restrict__ ed, int* __restrict__ rowstart,
                            float* __restrict__ dinv) {
    __shared__ int lcnt[256];
    __shared__ int lofs[256];
    __shared__ int lcur[256];
    int tid = threadIdx.x;
    int b = blockIdx.x;
    int node0 = b << 8;
    int start = bucketbase[b], end = bucketbase[b + 1];
    int cnt = end - start;
    lcnt[tid] = 0;
    lcur[tid] = 0;
    __syncthreads();

    int head = min((4 - (start & 3)) & 3, cnt);
    int body = (cnt - head) & ~3;
    const uint4* sp = (const uint4*)(staging + start + head);

    for (int i = tid; i < head; i += 256)
        atomicAdd(&lcnt[staging[start + i] >> 17], 1);
    for (int i = tid; i < (body >> 2); i += 256) {
        uint4 q = sp[i];
        atomicAdd(&lcnt[q.x >> 17], 1);
        atomicAdd(&lcnt[q.y >> 17], 1);
        atomicAdd(&lcnt[q.z >> 17], 1);
        atomicAdd(&lcnt[q.w >> 17], 1);
    }
    for (int i = head + body + tid; i < cnt; i += 256)
        atomicAdd(&lcnt[staging[start + i] >> 17], 1);
    __syncthreads();

    int val = lcnt[tid];
    lofs[tid] = val;
    __syncthreads();
    for (int off = 1; off < 256; off <<= 1) {
        int t = (tid >= off) ? lofs[tid - off] : 0;
        __syncthreads();
        lofs[tid] += t;
        __syncthreads();
    }
    int ex = lofs[tid] - val;
    __syncthreads();
    lofs[tid] = ex;
    __syncthreads();
    int node = node0 + tid;
    if (node < n) {
        rowstart[node] = start + ex;
        dinv[node] = rsqrtf((float)(val + 1));
    }
    if (node == 0) rowstart[n] = E;

    for (int i = tid; i < head; i += 256) {
        unsigned w = staging[start + i];
        int ld = (int)(w >> 17);
        int pos = start + lofs[ld] + atomicAdd(&lcur[ld], 1);
        ed[pos] = (int)(w & 0x1FFFFu);
    }
    for (int i = tid; i < (body >> 2); i += 256) {
        uint4 q = sp[i];
        int ld = (int)(q.x >> 17);
        int pos = start + lofs[ld] + atomicAdd(&lcur[ld], 1);
        ed[pos] = (int)(q.x & 0x1FFFFu);
        ld = (int)(q.y >> 17);
        pos = start + lofs[ld] + atomicAdd(&lcur[ld], 1);
        ed[pos] = (int)(q.y & 0x1FFFFu);
        ld = (int)(q.z >> 17);
        pos = start + lofs[ld] + atomicAdd(&lcur[ld], 1);
        ed[pos] = (int)(q.z & 0x1FFFFu);
        ld = (int)(q.w >> 17);
        pos = start + lofs[ld] + atomicAdd(&lcur[ld], 1);
        ed[pos] = (int)(q.w & 0x1FFFFu);
    }
    for (int i = head + body + tid; i < cnt; i += 256) {
        unsigned w = staging[start + i];
        int ld = (int)(w >> 17);
        int pos = start + lofs[ld] + atomicAdd(&lcur[ld], 1);
        ed[pos] = (int)(w & 0x1FFFFu);
    }
}

// ---------- layer 0 dense transform: hw0 = bf16(dinv * (x @ W0)), x staged in LDS ----------
__global__ void t0_kernel(const float* __restrict__ x, const float* __restrict__ W0,
                          const float* __restrict__ dinv,
                          __hip_bfloat16* __restrict__ hw, int n) {
    __shared__ float Wl[F_IN * H];
    __shared__ float xs[NPB * F_IN];
    int tid = threadIdx.x;
    for (int j = tid; j < F_IN * H; j += 256) Wl[j] = W0[j];
    int v0 = blockIdx.x * NPB;
    int nrows = min(NPB, n - v0);
    int nfl = nrows * F_IN;
    const float* xb = x + (size_t)v0 * F_IN;
    int nf4 = nfl >> 2;
    for (int j = tid; j < nf4; j += 256)
        ((float4*)xs)[j] = ((const float4*)xb)[j];
    for (int j = (nf4 << 2) + tid; j < nfl; j += 256)
        xs[j] = xb[j];
    __syncthreads();
    int g = tid >> 4, f = tid & 15;
    int v = v0 + g;
    if (v >= n) return;
    const float* xr = xs + g * F_IN;
    float acc = 0.f;
#pragma unroll
    for (int k = 0; k < F_IN; ++k) acc += xr[k] * Wl[k * H + f];
    hw[v * H + f] = __float2bfloat16(acc * dinv[v]);
}

// ---------- gather macro shared by both agg kernels ----------
#define GATHER8(IDX0, ACC_A, ACC_B)                                                        \
    {                                                                                      \
        int t0 = (IDX0)[0], t1 = (IDX0)[1], t2 = (IDX0)[2], t3 = (IDX0)[3];                \
        int t4 = (IDX0)[4], t5 = (IDX0)[5], t6 = (IDX0)[6], t7 = (IDX0)[7];                \
        ushort4 u0 = *(const ushort4*)(hwu + t0 * H + fb);                                 \
        ushort4 u1 = *(const ushort4*)(hwu + t1 * H + fb);                                 \
        ushort4 u2 = *(const ushort4*)(hwu + t2 * H + fb);                                 \
        ushort4 u3 = *(const ushort4*)(hwu + t3 * H + fb);                                 \
        ushort4 u4 = *(const ushort4*)(hwu + t4 * H + fb);                                 \
        ushort4 u5 = *(const ushort4*)(hwu + t5 * H + fb);                                 \
        ushort4 u6 = *(const ushort4*)(hwu + t6 * H + fb);                                 \
        ushort4 u7 = *(const ushort4*)(hwu + t7 * H + fb);                                 \
        ACC_A.x += bfu2f(u0.x); ACC_A.y += bfu2f(u0.y); ACC_A.z += bfu2f(u0.z); ACC_A.w += bfu2f(u0.w); \
        ACC_B.x += bfu2f(u1.x); ACC_B.y += bfu2f(u1.y); ACC_B.z += bfu2f(u1.z); ACC_B.w += bfu2f(u1.w); \
        ACC_A.x += bfu2f(u2.x); ACC_A.y += bfu2f(u2.y); ACC_A.z += bfu2f(u2.z); ACC_A.w += bfu2f(u2.w); \
        ACC_B.x += bfu2f(u3.x); ACC_B.y += bfu2f(u3.y); ACC_B.z += bfu2f(u3.z); ACC_B.w += bfu2f(u3.w); \
        ACC_A.x += bfu2f(u4.x); ACC_A.y += bfu2f(u4.y); ACC_A.z += bfu2f(u4.z); ACC_A.w += bfu2f(u4.w); \
        ACC_B.x += bfu2f(u5.x); ACC_B.y += bfu2f(u5.y); ACC_B.z += bfu2f(u5.z); ACC_B.w += bfu2f(u5.w); \
        ACC_A.x += bfu2f(u6.x); ACC_A.y += bfu2f(u6.y); ACC_A.z += bfu2f(u6.z); ACC_A.w += bfu2f(u6.w); \
        ACC_B.x += bfu2f(u7.x); ACC_B.y += bfu2f(u7.y); ACC_B.z += bfu2f(u7.z); ACC_B.w += bfu2f(u7.w); \
    }

// ---------- fallback aggregation (round-12 path, one dispatch per layer) ----------
__global__ __launch_bounds__(256) void agg_kernel(
    const int* __restrict__ ed, const int* __restrict__ rowstart,
    const float* __restrict__ dinv, const __hip_bfloat16* __restrict__ hw,
    const float* __restrict__ bias, const float* __restrict__ Wnext,
    float* __restrict__ jk, __hip_bfloat16* __restrict__ hw_next,
    const float* __restrict__ fcw, const float* __restrict__ fcb,
    float* __restrict__ out,
    int n, int first, int has_next, int last) {
    __shared__ float Wl[H * H];
    __shared__ int eds[ECAP + 8];
    __shared__ int rs[65];
    int tid = threadIdx.x;
    if (has_next) Wl[tid] = Wnext[tid];
    int node0 = blockIdx.x * 64;
    int nn = min(64, n - node0);
    if (tid <= nn) rs[tid] = rowstart[node0 + tid];
    __syncthreads();
    int s0 = rs[0];
    int aoff = s0 & 3;
    int cnt = rs[nn] - s0;
    bool lds_ok = (cnt + aoff) <= ECAP;
    if (lds_ok) {
        int m4 = (cnt + aoff + 3) >> 2;
        const int4* ep = (const int4*)(ed + (s0 - aoff));
        for (int i = tid; i < m4; i += 256)
            *(int4*)&eds[4 * i] = ep[i];
    }
    __syncthreads();

    int g = tid >> 2, l = tid & 3;
    if (g >= nn) return;
    int v = node0 + g;
    int fb = l * 4;
    const unsigned short* hwu = (const unsigned short*)hw;

    float4 accA = make_float4(0.f, 0.f, 0.f, 0.f);
    float4 accB = make_float4(0.f, 0.f, 0.f, 0.f);

    if (lds_ok) {
        int ls = rs[g] - s0 + aoff, le = rs[g + 1] - s0 + aoff;
        int i = ls;
        for (; i + 8 <= le; i += 8) GATHER8(&eds[i], accA, accB)
        for (; i < le; ++i) {
            ushort4 u = *(const ushort4*)(hwu + eds[i] * H + fb);
            accA.x += bfu2f(u.x); accA.y += bfu2f(u.y); accA.z += bfu2f(u.z); accA.w += bfu2f(u.w);
        }
    } else {
        int i = rs[g], e = rs[g + 1];
        for (; i + 8 <= e; i += 8) GATHER8(&ed[i], accA, accB)
        for (; i < e; ++i) {
            ushort4 u = *(const ushort4*)(hwu + ed[i] * H + fb);
            accA.x += bfu2f(u.x); accA.y += bfu2f(u.y); accA.z += bfu2f(u.z); accA.w += bfu2f(u.w);
        }
    }

    ushort4 us = *(const ushort4*)(hwu + (size_t)v * H + fb);
    float dv = dinv[v];
    float4 bv = *(const float4*)(bias + fb);
    float4 val;
    val.x = fmaxf((accA.x + accB.x + bfu2f(us.x)) * dv + bv.x, 0.f);
    val.y = fmaxf((accA.y + accB.y + bfu2f(us.y)) * dv + bv.y, 0.f);
    val.z = fmaxf((accA.z + accB.z + bfu2f(us.z)) * dv + bv.z, 0.f);
    val.w = fmaxf((accA.w + accB.w + bfu2f(us.w)) * dv + bv.w, 0.f);

    float4* jkp = (float4*)(jk + (size_t)v * H + fb);
    float4 jv = val;
    if (!first) {
        float4 jo = *jkp;
        jv.x = fmaxf(jo.x, val.x); jv.y = fmaxf(jo.y, val.y);
        jv.z = fmaxf(jo.z, val.z); jv.w = fmaxf(jo.w, val.w);
    }
    if (!last) {
        *jkp = jv;
    } else {
        float4 wv = *(const float4*)(fcw + fb);
        float partial = jv.x * wv.x + jv.y * wv.y + jv.z * wv.z + jv.w * wv.w;
        partial += __shfl_xor(partial, 1, 4);
        partial += __shfl_xor(partial, 2, 4);
        if (l == 0) out[v] = partial + fcb[0];
    }

    if (has_next) {
        float4 o = make_float4(0.f, 0.f, 0.f, 0.f);
#pragma unroll
        for (int kq = 0; kq < 4; ++kq) {
            float4 vk;
            vk.x = __shfl(val.x, kq, 4);
            vk.y = __shfl(val.y, kq, 4);
            vk.z = __shfl(val.z, kq, 4);
            vk.w = __shfl(val.w, kq, 4);
            float4 w0 = *(const float4*)(Wl + (4 * kq + 0) * H + fb);
            float4 w1 = *(const float4*)(Wl + (4 * kq + 1) * H + fb);
            float4 w2 = *(const float4*)(Wl + (4 * kq + 2) * H + fb);
            float4 w3 = *(const float4*)(Wl + (4 * kq + 3) * H + fb);
            o.x += vk.x * w0.x + vk.y * w1.x + vk.z * w2.x + vk.w * w3.x;
            o.y += vk.x * w0.y + vk.y * w1.y + vk.z * w2.y + vk.w * w3.y;
            o.z += vk.x * w0.z + vk.y * w1.z + vk.z * w2.z + vk.w * w3.z;
            o.w += vk.x * w0.w + vk.y * w1.w + vk.z * w2.w + vk.w * w3.w;
        }
        ushort4 ob;
        ob.x = (unsigned short)(__bfloat16_as_ushort(__float2bfloat16(o.x * dv)));
        ob.y = (unsigned short)(__bfloat16_as_ushort(__float2bfloat16(o.y * dv)));
        ob.z = (unsigned short)(__bfloat16_as_ushort(__float2bfloat16(o.z * dv)));
        ob.w = (unsigned short)(__bfloat16_as_ushort(__float2bfloat16(o.w * dv)));
        *(ushort4*)((unsigned short*)hw_next + (size_t)v * H + fb) = ob;
    }
}

// ---------- cooperative fused aggregation: all L layers in one kernel ----------
// eds/rs staged in LDS ONCE for all layers; jk lives in registers; grid.sync between layers.
__global__ __launch_bounds__(256, 4) void agg_coop_kernel(
    const int* __restrict__ ed, const int* __restrict__ rowstart,
    const float* __restrict__ dinv,
    __hip_bfloat16* __restrict__ hwA, __hip_bfloat16* __restrict__ hwB,
    const float* __restrict__ bs, const float* __restrict__ Ws,
    const float* __restrict__ fcw, const float* __restrict__ fcb,
    float* __restrict__ out, int n, int L, int nwin, int G) {
    cg::grid_group grid = cg::this_grid();
    __shared__ float Wl[H * H];
    __shared__ int eds[MAXW][WECAP + 8];
    __shared__ int rs[MAXW][65];
    int tid = threadIdx.x;
    int bid = blockIdx.x;

    int nw = 0;
#pragma unroll
    for (int wi = 0; wi < MAXW; ++wi) {
        int w = bid + wi * G;
        if (w < nwin) {
            nw = wi + 1;
            int node0 = w << 6;
            int nn = min(64, n - node0);
            if (tid <= nn) rs[wi][tid] = rowstart[node0 + tid];
        }
    }
    __syncthreads();
    bool ldsok0 = true, ldsok1 = true;
#pragma unroll
    for (int wi = 0; wi < MAXW; ++wi) {
        if (wi < nw) {
            int w = bid + wi * G;
            int node0 = w << 6;
            int nn = min(64, n - node0);
            int s0 = rs[wi][0];
            int aoff = s0 & 3;
            int cnt = rs[wi][nn] - s0;
            bool ok = (cnt + aoff) <= WECAP;
            if (wi == 0) ldsok0 = ok; else ldsok1 = ok;
            if (ok) {
                int m4 = (cnt + aoff + 3) >> 2;
                const int4* ep = (const int4*)(ed + (s0 - aoff));
                for (int i = tid; i < m4; i += 256)
                    *(int4*)&eds[wi][4 * i] = ep[i];
            }
        }
    }
    __syncthreads();

    int g = tid >> 2, l4 = tid & 3;
    int fb = l4 * 4;
    float4 jkreg[MAXW];

    for (int l = 0; l < L; ++l) {
        const unsigned short* hwu = (const unsigned short*)((l & 1) ? hwB : hwA);
        unsigned short* nxt = (unsigned short*)((l & 1) ? hwA : hwB);
        int has_next = (l < L - 1);
        const float* bias = bs + (size_t)l * H;
        if (has_next) Wl[tid] = Ws[(size_t)l * H * H + tid];
        __syncthreads();

#pragma unroll
        for (int wi = 0; wi < MAXW; ++wi) {
            if (wi < nw) {
                int w = bid + wi * G;
                int node0 = w << 6;
                int nn = min(64, n - node0);
                bool ok = (wi == 0) ? ldsok0 : ldsok1;
                if (g < nn) {
                    int v = node0 + g;
                    int s0 = rs[wi][0];
                    int aoff = s0 & 3;
                    float4 accA = make_float4(0.f, 0.f, 0.f, 0.f);
                    float4 accB = make_float4(0.f, 0.f, 0.f, 0.f);
                    if (ok) {
                        int ls = rs[wi][g] - s0 + aoff, le = rs[wi][g + 1] - s0 + aoff;
                        int i = ls;
                        for (; i + 8 <= le; i += 8) GATHER8(&eds[wi][i], accA, accB)
                        for (; i < le; ++i) {
                            ushort4 u = *(const ushort4*)(hwu + eds[wi][i] * H + fb);
                            accA.x += bfu2f(u.x); accA.y += bfu2f(u.y);
                            accA.z += bfu2f(u.z); accA.w += bfu2f(u.w);
                        }
                    } else {
                        int i = rs[wi][g], e = rs[wi][g + 1];
                        for (; i + 8 <= e; i += 8) GATHER8(&ed[i], accA, accB)
                        for (; i < e; ++i) {
                            ushort4 u = *(const ushort4*)(hwu + ed[i] * H + fb);
                            accA.x += bfu2f(u.x); accA.y += bfu2f(u.y);
                            accA.z += bfu2f(u.z); accA.w += bfu2f(u.w);
                        }
                    }

                    ushort4 us = *(const ushort4*)(hwu + (size_t)v * H + fb);
                    float dv = dinv[v];
                    float4 bv = *(const float4*)(bias + fb);
                    float4 val;
                    val.x = fmaxf((accA.x + accB.x + bfu2f(us.x)) * dv + bv.x, 0.f);
                    val.y = fmaxf((accA.y + accB.y + bfu2f(us.y)) * dv + bv.y, 0.f);
                    val.z = fmaxf((accA.z + accB.z + bfu2f(us.z)) * dv + bv.z, 0.f);
                    val.w = fmaxf((accA.w + accB.w + bfu2f(us.w)) * dv + bv.w, 0.f);

                    float4 jv;
                    if (l == 0) {
                        jv = val;
                    } else {
                        jv.x = fmaxf(jkreg[wi].x, val.x);
                        jv.y = fmaxf(jkreg[wi].y, val.y);
                        jv.z = fmaxf(jkreg[wi].z, val.z);
                        jv.w = fmaxf(jkreg[wi].w, val.w);
                    }
                    jkreg[wi] = jv;

                    if (l == L - 1) {
                        float4 wv = *(const float4*)(fcw + fb);
                        float partial = jv.x * wv.x + jv.y * wv.y + jv.z * wv.z + jv.w * wv.w;
                        partial += __shfl_xor(partial, 1, 4);
                        partial += __shfl_xor(partial, 2, 4);
                        if (l4 == 0) out[v] = partial + fcb[0];
                    }

                    if (has_next) {
                        float4 o = make_float4(0.f, 0.f, 0.f, 0.f);
#pragma unroll
                        for (int kq = 0; kq < 4; ++kq) {
                            float4 vk;
                            vk.x = __shfl(val.x, kq, 4);
                            vk.y = __shfl(val.y, kq, 4);
                            vk.z = __shfl(val.z, kq, 4);
                            vk.w = __shfl(val.w, kq, 4);
                            float4 w0 = *(const float4*)(Wl + (4 * kq + 0) * H + fb);
                            float4 w1 = *(const float4*)(Wl + (4 * kq + 1) * H + fb);
                            float4 w2 = *(const float4*)(Wl + (4 * kq + 2) * H + fb);
                            float4 w3 = *(const float4*)(Wl + (4 * kq + 3) * H + fb);
                            o.x += vk.x * w0.x + vk.y * w1.x + vk.z * w2.x + vk.w * w3.x;
                            o.y += vk.x * w0.y + vk.y * w1.y + vk.z * w2.y + vk.w * w3.y;
                            o.z += vk.x * w0.z + vk.y * w1.z + vk.z * w2.z + vk.w * w3.z;
                            o.w += vk.x * w0.w + vk.y * w1.w + vk.z * w2.w + vk.w * w3.w;
                        }
                        ushort4 ob;
                        ob.x = (unsigned short)(__bfloat16_as_ushort(__float2bfloat16(o.x * dv)));
                        ob.y = (unsigned short)(__bfloat16_as_ushort(__float2bfloat16(o.y * dv)));
                        ob.z = (unsigned short)(__bfloat16_as_ushort(__float2bfloat16(o.z * dv)));
                        ob.w = (unsigned short)(__bfloat16_as_ushort(__float2bfloat16(o.w * dv)));
                        *(ushort4*)(nxt + (size_t)v * H + fb) = ob;
                    }
                }
            }
        }
        if (has_next) grid.sync();
    }
}

extern "C" void kernel_launch(void* const* d_in, const int* in_sizes, int n_in,
                              void* d_out, int out_size, void* d_ws, size_t ws_size,
                              hipStream_t stream) {
    const float* x    = (const float*)d_in[0];
    const void*  eidx = d_in[1];
    const float* W0   = (const float*)d_in[2];
    const float* Ws   = (const float*)d_in[3];
    const float* bs   = (const float*)d_in[4];
    const float* fc_w = (const float*)d_in[5];
    const float* fc_b = (const float*)d_in[6];

    int n = in_sizes[0] / F_IN;        // 100000
    int E = in_sizes[1] / 2;           // 3200000
    int L = in_sizes[4] / H;           // 10

    // workspace carve-up
    char* w = (char*)d_ws;
    size_t off = 0;
    int* rowstart    = (int*)(w + off); off += align256((size_t)(n + 1) * 4);
    float* dinv      = (float*)(w + off); off += align256((size_t)n * 4);
    int* bucketcnt   = (int*)(w + off); off += align256(512 * 4);
    int* bucketbase  = (int*)(w + off); off += align256(513 * 4);
    int* gcur        = (int*)(w + off); off += align256(512 * 4);
    int* flag64      = (int*)(w + off); off += align256(256);
    unsigned* stg    = (unsigned*)(w + off); off += align256((size_t)E * 4);
    int* ed          = (int*)(w + off); off += align256((size_t)E * 4 + 64);
    __hip_bfloat16* hwA = (__hip_bfloat16*)(w + off); off += align256((size_t)n * H * 2);
    __hip_bfloat16* hwB = (__hip_bfloat16*)(w + off); off += align256((size_t)n * H * 2);
    float* jk        = (float*)(w + off); off += align256((size_t)n * H * 4);

    int NB = (n + 255) / 256;          // 391 buckets of 256 nodes

    hipMemsetAsync(bucketcnt, 0, 512 * 4, stream);
    detect_kernel<<<1, 256, 0, stream>>>((const int*)eidx, flag64);
    bcount_kernel<<<512, 256, 0, stream>>>(eidx, E, flag64, n, bucketcnt);
    bscan_kernel<<<1, 512, 0, stream>>>(bucketcnt, NB, E, gcur, bucketbase);
    int SG = (E + 4095) / 4096;        // chunk <= 4096 <= SCH
    stage_kernel<<<SG, 256, 0, stream>>>(eidx, E, flag64, n, gcur, stg);
    fine_kernel<<<NB, 256, 0, stream>>>(stg, bucketbase, n, E, ed, rowstart, dinv);

    int ngrid = (n + NPB - 1) / NPB;   // 6250
    t0_kernel<<<ngrid, 256, 0, stream>>>(x, W0, dinv, hwA, n);

    int nwin = (n + 63) / 64;          // 1563
    int G = (nwin + MAXW - 1) / MAXW;  // 782

    // cooperative-launch feasibility (host-side queries, capture-safe)
    int coop = 0;
    hipDeviceGetAttribute(&coop, hipDeviceAttributeCooperativeLaunch, 0);
    int occ = 0;
    hipOccupancyMaxActiveBlocksPerMultiprocessor(&occ, agg_coop_kernel, 256, 0);
    int numCU = 0;
    hipDeviceGetAttribute(&numCU, hipDeviceAttributeMultiprocessorCount, 0);
    bool useCoop = coop && ((long)occ * numCU >= G);

    if (useCoop) {
        float* outp = (float*)d_out;
        void* args[] = { (void*)&ed, (void*)&rowstart, (void*)&dinv,
                         (void*)&hwA, (void*)&hwB, (void*)&bs, (void*)&Ws,
                         (void*)&fc_w, (void*)&fc_b, (void*)&outp,
                         (void*)&n, (void*)&L, (void*)&nwin, (void*)&G };
        hipLaunchCooperativeKernel((void*)agg_coop_kernel, dim3(G), dim3(256),
                                   args, 0, stream);
    } else {
        __hip_bfloat16* cur = hwA;
        __hip_bfloat16* nxt = hwB;
        for (int l = 0; l < L; ++l) {
            const float* bias  = bs + (size_t)l * H;
            const float* Wnext = (l < L - 1) ? (Ws + (size_t)l * H * H) : nullptr;
            agg_kernel<<<nwin, 256, 0, stream>>>(ed, rowstart, dinv, cur, bias, Wnext,
                                                 jk, nxt, fc_w, fc_b, (float*)d_out,
                                                 n, (l == 0) ? 1 : 0,
                                                 (l < L - 1) ? 1 : 0,
                                                 (l == L - 1) ? 1 : 0);
            __hip_bfloat16* t = cur; cur = nxt; nxt = t;
        }
    }
}

// Round 14
// 339.605 us; speedup vs baseline: 1.0020x; 1.0020x over previous
//
#include <hip/hip_runtime.h>
#include <hip/hip_bf16.h>

#define H 16
#define F_IN 58
#define NPB 16     // nodes per block in t0 (256 threads / 16 lanes)
#define SCH 4160   // max edges per stage chunk (LDS sort capacity)
#define ECAP 4096  // LDS edge-cache capacity in agg (64 nodes * avg 32 = 2048 typ)

static inline size_t align256(size_t x) { return (x + 255) & ~(size_t)255; }

__device__ inline float bfu2f(unsigned short u) {
    return __uint_as_float(((unsigned)u) << 16);
}

// ---------- dtype detection: int64 vs int32 edge_index ----------
__global__ void detect_kernel(const int* eidx32, int* flag) {
    __shared__ int any;
    if (threadIdx.x == 0) any = 0;
    __syncthreads();
    int nz = 0;
    for (int j = threadIdx.x; j < 1024; j += 256)
        nz |= (eidx32[2 * j + 1] != 0);
    if (nz) atomicOr(&any, 1);
    __syncthreads();
    if (threadIdx.x == 0) *flag = (any == 0) ? 1 : 0;  // all-zero odd words -> int64
}

__device__ inline int load_idx(const void* eidx, long i, int is64) {
    if (is64) return (int)((const long long*)eidx)[i];
    return ((const int*)eidx)[i];
}

// ---------- bucket counts (391 bins of 256 nodes), vectorized dst reads ----------
__global__ void bcount_kernel(const void* eidx, int E, const int* flag64,
                              int n, int* bucketcnt) {
    __shared__ int hist[512];
    int is64 = *flag64;
    int B = (n + 255) >> 8;
    int tid = threadIdx.x;
    for (int j = tid; j < B; j += 256) hist[j] = 0;
    __syncthreads();
    int stride = gridDim.x * blockDim.x;
    int gid = blockIdx.x * blockDim.x + tid;
    if (is64) {
        const longlong2* d2 = (const longlong2*)((const long long*)eidx + E);
        int half = E >> 1;
        for (int i = gid; i < half; i += stride) {
            longlong2 q = d2[i];
            atomicAdd(&hist[((int)q.x) >> 8], 1);
            atomicAdd(&hist[((int)q.y) >> 8], 1);
        }
        if (gid == 0 && (E & 1)) {
            int d = (int)((const long long*)eidx)[2 * (long)E - 1];
            atomicAdd(&hist[d >> 8], 1);
        }
    } else {
        const int4* d4 = (const int4*)((const int*)eidx + E);
        int quarter = E >> 2;
        for (int i = gid; i < quarter; i += stride) {
            int4 q = d4[i];
            atomicAdd(&hist[q.x >> 8], 1);
            atomicAdd(&hist[q.y >> 8], 1);
            atomicAdd(&hist[q.z >> 8], 1);
            atomicAdd(&hist[q.w >> 8], 1);
        }
        for (int i = (quarter << 2) + gid; i < E; i += stride) {
            int d = ((const int*)eidx)[(long)E + i];
            atomicAdd(&hist[d >> 8], 1);
        }
    }
    __syncthreads();
    for (int j = tid; j < B; j += 256)
        if (hist[j]) atomicAdd(&bucketcnt[j], hist[j]);
}

// ---------- exclusive scan of bucket counts (single block, B <= 512) ----------
__global__ void bscan_kernel(const int* bucketcnt, int B, int E,
                             int* gcur, int* bucketbase) {
    __shared__ int tmp[512];
    int tid = threadIdx.x;
    int val = (tid < B) ? bucketcnt[tid] : 0;
    tmp[tid] = val;
    __syncthreads();
    for (int off = 1; off < 512; off <<= 1) {
        int t = (tid >= off) ? tmp[tid - off] : 0;
        __syncthreads();
        tmp[tid] += t;
        __syncthreads();
    }
    if (tid < B) {
        int ex = tmp[tid] - val;
        gcur[tid] = ex;
        bucketbase[tid] = ex;
    }
    if (tid == 0) bucketbase[B] = E;
}

// ---------- stage: LDS counting-sort each chunk by bucket, write coalesced runs ----------
__global__ void stage_kernel(const void* eidx, int E, const int* flag64,
                             int n, int* gcur, unsigned* staging) {
    __shared__ unsigned sorted[SCH];
    __shared__ unsigned short sbuck[SCH];
    __shared__ int hist[512];
    __shared__ int hbase[512];
    __shared__ int lofs[512];
    __shared__ int cursor[512];
    __shared__ int ps[256];

    int is64 = *flag64;
    int tid = threadIdx.x;
    int chunk = (E + gridDim.x - 1) / gridDim.x;
    int s0 = blockIdx.x * chunk;
    int s1 = min(E, s0 + chunk);
    int c = s1 - s0;
    if (c <= 0) return;

    for (int j = tid; j < 512; j += 256) { hist[j] = 0; cursor[j] = 0; }
    __syncthreads();

    // pass A: per-chunk bucket histogram (vectorized dst reads)
    if (is64) {
        const longlong2* dp = (const longlong2*)((const long long*)eidx + E + s0);
        int m = c >> 1;
        for (int i = tid; i < m; i += 256) {
            longlong2 q = dp[i];
            atomicAdd(&hist[((int)q.x) >> 8], 1);
            atomicAdd(&hist[((int)q.y) >> 8], 1);
        }
        if (tid == 0 && (c & 1)) {
            int d = (int)((const long long*)eidx)[(long)E + s1 - 1];
            atomicAdd(&hist[d >> 8], 1);
        }
    } else {
        const int2* dp = (const int2*)((const int*)eidx + E + s0);
        int m = c >> 1;
        for (int i = tid; i < m; i += 256) {
            int2 q = dp[i];
            atomicAdd(&hist[q.x >> 8], 1);
            atomicAdd(&hist[q.y >> 8], 1);
        }
        if (tid == 0 && (c & 1)) {
            int d = ((const int*)eidx)[(long)E + s1 - 1];
            atomicAdd(&hist[d >> 8], 1);
        }
    }
    __syncthreads();

    // pass B: reserve global run per bucket
    for (int j = tid; j < 512; j += 256) {
        int cc = hist[j];
        hbase[j] = cc ? atomicAdd(&gcur[j], cc) : 0;
    }

    // pass C: exclusive scan of hist -> lofs (512 bins, 256 threads)
    int a0 = hist[2 * tid], a1 = hist[2 * tid + 1];
    ps[tid] = a0 + a1;
    __syncthreads();
    for (int off = 1; off < 256; off <<= 1) {
        int t = (tid >= off) ? ps[tid - off] : 0;
        __syncthreads();
        ps[tid] += t;
        __syncthreads();
    }
    int ex = ps[tid] - (a0 + a1);
    lofs[2 * tid] = ex;
    lofs[2 * tid + 1] = ex + a0;
    __syncthreads();

    // pass D: scatter into LDS in bucket-sorted order (vectorized src+dst reads)
    if (is64) {
        const longlong2* sp = (const longlong2*)((const long long*)eidx + s0);
        const longlong2* dp = (const longlong2*)((const long long*)eidx + E + s0);
        int m = c >> 1;
        for (int i = tid; i < m; i += 256) {
            longlong2 qs = sp[i];
            longlong2 qd = dp[i];
            int s = (int)qs.x, d = (int)qd.x;
            int b = d >> 8;
            int loc = lofs[b] + atomicAdd(&cursor[b], 1);
            sorted[loc] = (unsigned)s | ((unsigned)(d & 255) << 17);
            sbuck[loc] = (unsigned short)b;
            s = (int)qs.y; d = (int)qd.y;
            b = d >> 8;
            loc = lofs[b] + atomicAdd(&cursor[b], 1);
            sorted[loc] = (unsigned)s | ((unsigned)(d & 255) << 17);
            sbuck[loc] = (unsigned short)b;
        }
        if (tid == 0 && (c & 1)) {
            int s = (int)((const long long*)eidx)[(long)s1 - 1];
            int d = (int)((const long long*)eidx)[(long)E + s1 - 1];
            int b = d >> 8;
            int loc = lofs[b] + atomicAdd(&cursor[b], 1);
            sorted[loc] = (unsigned)s | ((unsigned)(d & 255) << 17);
            sbuck[loc] = (unsigned short)b;
        }
    } else {
        const int2* sp = (const int2*)((const int*)eidx + s0);
        const int2* dp = (const int2*)((const int*)eidx + E + s0);
        int m = c >> 1;
        for (int i = tid; i < m; i += 256) {
            int2 qs = sp[i];
            int2 qd = dp[i];
            int b = qd.x >> 8;
            int loc = lofs[b] + atomicAdd(&cursor[b], 1);
            sorted[loc] = (unsigned)qs.x | ((unsigned)(qd.x & 255) << 17);
            sbuck[loc] = (unsigned short)b;
            b = qd.y >> 8;
            loc = lofs[b] + atomicAdd(&cursor[b], 1);
            sorted[loc] = (unsigned)qs.y | ((unsigned)(qd.y & 255) << 17);
            sbuck[loc] = (unsigned short)b;
        }
        if (tid == 0 && (c & 1)) {
            int s = ((const int*)eidx)[(long)s1 - 1];
            int d = ((const int*)eidx)[(long)E + s1 - 1];
            int b = d >> 8;
            int loc = lofs[b] + atomicAdd(&cursor[b], 1);
            sorted[loc] = (unsigned)s | ((unsigned)(d & 255) << 17);
            sbuck[loc] = (unsigned short)b;
        }
    }
    __syncthreads();

    // pass E: linear LDS read, coalesced run writes to global
    for (int i = tid; i < c; i += 256) {
        int b = sbuck[i];
        staging[hbase[b] + (i - lofs[b])] = sorted[i];
    }
}

// ---------- per-bucket local hist + scan -> rowstart/dinv, node-sorted ed ----------
// stg reads vectorized (order-independent passes; scalar head/tail, no cross-bucket reads)
__global__ void fine_kernel(const unsigned* __restrict__ staging,
                            const int* __restrict__ bucketbase, int n, int E,
                            int* __restrict__ ed, int* __restrict__ rowstart,
                            float* __restrict__ dinv) {
    __shared__ int lcnt[256];
    __shared__ int lofs[256];
    __shared__ int lcur[256];
    int tid = threadIdx.x;
    int b = blockIdx.x;
    int node0 = b << 8;
    int start = bucketbase[b], end = bucketbase[b + 1];
    int cnt = end - start;
    lcnt[tid] = 0;
    lcur[tid] = 0;
    __syncthreads();

    int head = min((4 - (start & 3)) & 3, cnt);
    int body = (cnt - head) & ~3;
    const uint4* sp = (const uint4*)(staging + start + head);

    // pass 1: per-node histogram
    for (int i = tid; i < head; i += 256)
        atomicAdd(&lcnt[staging[start + i] >> 17], 1);
    for (int i = tid; i < (body >> 2); i += 256) {
        uint4 q = sp[i];
        atomicAdd(&lcnt[q.x >> 17], 1);
        atomicAdd(&lcnt[q.y >> 17], 1);
        atomicAdd(&lcnt[q.z >> 17], 1);
        atomicAdd(&lcnt[q.w >> 17], 1);
    }
    for (int i = head + body + tid; i < cnt; i += 256)
        atomicAdd(&lcnt[staging[start + i] >> 17], 1);
    __syncthreads();

    int val = lcnt[tid];
    lofs[tid] = val;
    __syncthreads();
    for (int off = 1; off < 256; off <<= 1) {
        int t = (tid >= off) ? lofs[tid - off] : 0;
        __syncthreads();
        lofs[tid] += t;
        __syncthreads();
    }
    int ex = lofs[tid] - val;
    __syncthreads();
    lofs[tid] = ex;
    __syncthreads();
    int node = node0 + tid;
    if (node < n) {
        rowstart[node] = start + ex;
        dinv[node] = rsqrtf((float)(val + 1));
    }
    if (node == 0) rowstart[n] = E;

    // pass 2: node-sorted scatter (order-independent)
    for (int i = tid; i < head; i += 256) {
        unsigned w = staging[start + i];
        int ld = (int)(w >> 17);
        int pos = start + lofs[ld] + atomicAdd(&lcur[ld], 1);
        ed[pos] = (int)(w & 0x1FFFFu);
    }
    for (int i = tid; i < (body >> 2); i += 256) {
        uint4 q = sp[i];
        int ld = (int)(q.x >> 17);
        int pos = start + lofs[ld] + atomicAdd(&lcur[ld], 1);
        ed[pos] = (int)(q.x & 0x1FFFFu);
        ld = (int)(q.y >> 17);
        pos = start + lofs[ld] + atomicAdd(&lcur[ld], 1);
        ed[pos] = (int)(q.y & 0x1FFFFu);
        ld = (int)(q.z >> 17);
        pos = start + lofs[ld] + atomicAdd(&lcur[ld], 1);
        ed[pos] = (int)(q.z & 0x1FFFFu);
        ld = (int)(q.w >> 17);
        pos = start + lofs[ld] + atomicAdd(&lcur[ld], 1);
        ed[pos] = (int)(q.w & 0x1FFFFu);
    }
    for (int i = head + body + tid; i < cnt; i += 256) {
        unsigned w = staging[start + i];
        int ld = (int)(w >> 17);
        int pos = start + lofs[ld] + atomicAdd(&lcur[ld], 1);
        ed[pos] = (int)(w & 0x1FFFFu);
    }
}

// ---------- layer 0 dense transform: hw0 = bf16(dinv * (x @ W0)), x staged in LDS ----------
__global__ void t0_kernel(const float* __restrict__ x, const float* __restrict__ W0,
                          const float* __restrict__ dinv,
                          __hip_bfloat16* __restrict__ hw, int n) {
    __shared__ float Wl[F_IN * H];
    __shared__ float xs[NPB * F_IN];
    int tid = threadIdx.x;
    for (int j = tid; j < F_IN * H; j += 256) Wl[j] = W0[j];
    int v0 = blockIdx.x * NPB;
    int nrows = min(NPB, n - v0);
    int nfl = nrows * F_IN;
    const float* xb = x + (size_t)v0 * F_IN;   // 16*58*4 = 3712B: 16B aligned per block
    int nf4 = nfl >> 2;
    for (int j = tid; j < nf4; j += 256)
        ((float4*)xs)[j] = ((const float4*)xb)[j];
    for (int j = (nf4 << 2) + tid; j < nfl; j += 256)
        xs[j] = xb[j];
    __syncthreads();
    int g = tid >> 4, f = tid & 15;
    int v = v0 + g;
    if (v >= n) return;
    const float* xr = xs + g * F_IN;
    float acc = 0.f;
#pragma unroll
    for (int k = 0; k < F_IN; ++k) acc += xr[k] * Wl[k * H + f];
    hw[v * H + f] = __float2bfloat16(acc * dinv[v]);
}

// ---------- aggregation: 64 nodes/block, 4 lanes/node x 4 features, LDS edge cache ----------
// hw holds dinv-scaled features (bf16); agg = dinv[v]*(sum_src hw[src] + hw[v])
// Last layer fuses the FC: out[v] = dot(jk_max, fc_w) + fc_b (no jk store).
__global__ __launch_bounds__(256) void agg_kernel(
    const int* __restrict__ ed, const int* __restrict__ rowstart,
    const float* __restrict__ dinv, const __hip_bfloat16* __restrict__ hw,
    const float* __restrict__ bias, const float* __restrict__ Wnext,
    float* __restrict__ jk, __hip_bfloat16* __restrict__ hw_next,
    const float* __restrict__ fcw, const float* __restrict__ fcb,
    float* __restrict__ out,
    int n, int first, int has_next, int last) {
    __shared__ float Wl[H * H];
    __shared__ int eds[ECAP + 8];
    __shared__ int rs[65];
    int tid = threadIdx.x;
    if (has_next) Wl[tid] = Wnext[tid];  // 256 threads == 16x16
    int node0 = blockIdx.x * 64;
    int nn = min(64, n - node0);         // nodes in this block (>=1)
    if (tid <= nn) rs[tid] = rowstart[node0 + tid];
    __syncthreads();
    int s0 = rs[0];
    int aoff = s0 & 3;                   // eds[k] mirrors ed[s0 - aoff + k]
    int cnt = rs[nn] - s0;
    bool lds_ok = (cnt + aoff) <= ECAP;
    if (lds_ok) {
        int tot = cnt + aoff;
        int m4 = (tot + 3) >> 2;         // int4 count (over-read covered by slack)
        const int4* ep = (const int4*)(ed + (s0 - aoff));
        for (int i = tid; i < m4; i += 256)
            *(int4*)&eds[4 * i] = ep[i];
    }
    __syncthreads();

    int g = tid >> 2, l = tid & 3;       // 64 nodes/block, 4 lanes/node
    if (g >= nn) return;
    int v = node0 + g;
    int fb = l * 4;                      // feature quad base
    const unsigned short* hwu = (const unsigned short*)hw;

    float4 accA = make_float4(0.f, 0.f, 0.f, 0.f);
    float4 accB = make_float4(0.f, 0.f, 0.f, 0.f);

    if (lds_ok) {                        // fast path: indices from LDS
        int ls = rs[g] - s0 + aoff, le = rs[g + 1] - s0 + aoff;
        int i = ls;
        for (; i + 8 <= le; i += 8) {
            int t0 = eds[i],     t1 = eds[i + 1], t2 = eds[i + 2], t3 = eds[i + 3];
            int t4 = eds[i + 4], t5 = eds[i + 5], t6 = eds[i + 6], t7 = eds[i + 7];
            ushort4 u0 = *(const ushort4*)(hwu + t0 * H + fb);
            ushort4 u1 = *(const ushort4*)(hwu + t1 * H + fb);
            ushort4 u2 = *(const ushort4*)(hwu + t2 * H + fb);
            ushort4 u3 = *(const ushort4*)(hwu + t3 * H + fb);
            ushort4 u4 = *(const ushort4*)(hwu + t4 * H + fb);
            ushort4 u5 = *(const ushort4*)(hwu + t5 * H + fb);
            ushort4 u6 = *(const ushort4*)(hwu + t6 * H + fb);
            ushort4 u7 = *(const ushort4*)(hwu + t7 * H + fb);
            accA.x += bfu2f(u0.x); accA.y += bfu2f(u0.y); accA.z += bfu2f(u0.z); accA.w += bfu2f(u0.w);
            accB.x += bfu2f(u1.x); accB.y += bfu2f(u1.y); accB.z += bfu2f(u1.z); accB.w += bfu2f(u1.w);
            accA.x += bfu2f(u2.x); accA.y += bfu2f(u2.y); accA.z += bfu2f(u2.z); accA.w += bfu2f(u2.w);
            accB.x += bfu2f(u3.x); accB.y += bfu2f(u3.y); accB.z += bfu2f(u3.z); accB.w += bfu2f(u3.w);
            accA.x += bfu2f(u4.x); accA.y += bfu2f(u4.y); accA.z += bfu2f(u4.z); accA.w += bfu2f(u4.w);
            accB.x += bfu2f(u5.x); accB.y += bfu2f(u5.y); accB.z += bfu2f(u5.z); accB.w += bfu2f(u5.w);
            accA.x += bfu2f(u6.x); accA.y += bfu2f(u6.y); accA.z += bfu2f(u6.z); accA.w += bfu2f(u6.w);
            accB.x += bfu2f(u7.x); accB.y += bfu2f(u7.y); accB.z += bfu2f(u7.z); accB.w += bfu2f(u7.w);
        }
        for (; i < le; ++i) {
            ushort4 u = *(const ushort4*)(hwu + eds[i] * H + fb);
            accA.x += bfu2f(u.x); accA.y += bfu2f(u.y); accA.z += bfu2f(u.z); accA.w += bfu2f(u.w);
        }
    } else {                             // fallback: indices from global (huge block)
        int i = rs[g], e = rs[g + 1];
        for (; i + 8 <= e; i += 8) {
            int t0 = ed[i],     t1 = ed[i + 1], t2 = ed[i + 2], t3 = ed[i + 3];
            int t4 = ed[i + 4], t5 = ed[i + 5], t6 = ed[i + 6], t7 = ed[i + 7];
            ushort4 u0 = *(const ushort4*)(hwu + t0 * H + fb);
            ushort4 u1 = *(const ushort4*)(hwu + t1 * H + fb);
            ushort4 u2 = *(const ushort4*)(hwu + t2 * H + fb);
            ushort4 u3 = *(const ushort4*)(hwu + t3 * H + fb);
            ushort4 u4 = *(const ushort4*)(hwu + t4 * H + fb);
            ushort4 u5 = *(const ushort4*)(hwu + t5 * H + fb);
            ushort4 u6 = *(const ushort4*)(hwu + t6 * H + fb);
            ushort4 u7 = *(const ushort4*)(hwu + t7 * H + fb);
            accA.x += bfu2f(u0.x); accA.y += bfu2f(u0.y); accA.z += bfu2f(u0.z); accA.w += bfu2f(u0.w);
            accB.x += bfu2f(u1.x); accB.y += bfu2f(u1.y); accB.z += bfu2f(u1.z); accB.w += bfu2f(u1.w);
            accA.x += bfu2f(u2.x); accA.y += bfu2f(u2.y); accA.z += bfu2f(u2.z); accA.w += bfu2f(u2.w);
            accB.x += bfu2f(u3.x); accB.y += bfu2f(u3.y); accB.z += bfu2f(u3.z); accB.w += bfu2f(u3.w);
            accA.x += bfu2f(u4.x); accA.y += bfu2f(u4.y); accA.z += bfu2f(u4.z); accA.w += bfu2f(u4.w);
            accB.x += bfu2f(u5.x); accB.y += bfu2f(u5.y); accB.z += bfu2f(u5.z); accB.w += bfu2f(u5.w);
            accA.x += bfu2f(u6.x); accA.y += bfu2f(u6.y); accA.z += bfu2f(u6.z); accA.w += bfu2f(u6.w);
            accB.x += bfu2f(u7.x); accB.y += bfu2f(u7.y); accB.z += bfu2f(u7.z); accB.w += bfu2f(u7.w);
        }
        for (; i < e; ++i) {
            ushort4 u = *(const ushort4*)(hwu + ed[i] * H + fb);
            accA.x += bfu2f(u.x); accA.y += bfu2f(u.y); accA.z += bfu2f(u.z); accA.w += bfu2f(u.w);
        }
    }

    // self-loop + bias + relu
    ushort4 us = *(const ushort4*)(hwu + (size_t)v * H + fb);
    float dv = dinv[v];
    float4 bv = *(const float4*)(bias + fb);
    float4 val;
    val.x = fmaxf((accA.x + accB.x + bfu2f(us.x)) * dv + bv.x, 0.f);
    val.y = fmaxf((accA.y + accB.y + bfu2f(us.y)) * dv + bv.y, 0.f);
    val.z = fmaxf((accA.z + accB.z + bfu2f(us.z)) * dv + bv.z, 0.f);
    val.w = fmaxf((accA.w + accB.w + bfu2f(us.w)) * dv + bv.w, 0.f);

    // jk running max
    float4* jkp = (float4*)(jk + (size_t)v * H + fb);
    float4 jv = val;
    if (!first) {
        float4 jo = *jkp;
        jv.x = fmaxf(jo.x, val.x); jv.y = fmaxf(jo.y, val.y);
        jv.z = fmaxf(jo.z, val.z); jv.w = fmaxf(jo.w, val.w);
    }
    if (!last) {
        *jkp = jv;
    } else {
        // fused FC: out[v] = dot(jv_all16, fc_w) + fc_b
        float4 wv = *(const float4*)(fcw + fb);
        float partial = jv.x * wv.x + jv.y * wv.y + jv.z * wv.z + jv.w * wv.w;
        partial += __shfl_xor(partial, 1, 4);
        partial += __shfl_xor(partial, 2, 4);
        if (l == 0) out[v] = partial + fcb[0];
    }

    // fused next-layer transform: out[f'] = sum_k val_all[k] * W[k][f']
    if (has_next) {
        float4 o = make_float4(0.f, 0.f, 0.f, 0.f);
#pragma unroll
        for (int kq = 0; kq < 4; ++kq) {
            float4 vk;
            vk.x = __shfl(val.x, kq, 4);
            vk.y = __shfl(val.y, kq, 4);
            vk.z = __shfl(val.z, kq, 4);
            vk.w = __shfl(val.w, kq, 4);
            float4 w0 = *(const float4*)(Wl + (4 * kq + 0) * H + fb);
            float4 w1 = *(const float4*)(Wl + (4 * kq + 1) * H + fb);
            float4 w2 = *(const float4*)(Wl + (4 * kq + 2) * H + fb);
            float4 w3 = *(const float4*)(Wl + (4 * kq + 3) * H + fb);
            o.x += vk.x * w0.x + vk.y * w1.x + vk.z * w2.x + vk.w * w3.x;
            o.y += vk.x * w0.y + vk.y * w1.y + vk.z * w2.y + vk.w * w3.y;
            o.z += vk.x * w0.z + vk.y * w1.z + vk.z * w2.z + vk.w * w3.z;
            o.w += vk.x * w0.w + vk.y * w1.w + vk.z * w2.w + vk.w * w3.w;
        }
        ushort4 ob;
        ob.x = (unsigned short)(__bfloat16_as_ushort(__float2bfloat16(o.x * dv)));
        ob.y = (unsigned short)(__bfloat16_as_ushort(__float2bfloat16(o.y * dv)));
        ob.z = (unsigned short)(__bfloat16_as_ushort(__float2bfloat16(o.z * dv)));
        ob.w = (unsigned short)(__bfloat16_as_ushort(__float2bfloat16(o.w * dv)));
        *(ushort4*)((unsigned short*)hw_next + (size_t)v * H + fb) = ob;
    }
}

extern "C" void kernel_launch(void* const* d_in, const int* in_sizes, int n_in,
                              void* d_out, int out_size, void* d_ws, size_t ws_size,
                              hipStream_t stream) {
    const float* x    = (const float*)d_in[0];
    const void*  eidx = d_in[1];
    const float* W0   = (const float*)d_in[2];
    const float* Ws   = (const float*)d_in[3];
    const float* bs   = (const float*)d_in[4];
    const float* fc_w = (const float*)d_in[5];
    const float* fc_b = (const float*)d_in[6];

    int n = in_sizes[0] / F_IN;        // 100000
    int E = in_sizes[1] / 2;           // 3200000
    int L = in_sizes[4] / H;           // 10

    // workspace carve-up
    char* w = (char*)d_ws;
    size_t off = 0;
    int* rowstart    = (int*)(w + off); off += align256((size_t)(n + 1) * 4);
    float* dinv      = (float*)(w + off); off += align256((size_t)n * 4);
    int* bucketcnt   = (int*)(w + off); off += align256(512 * 4);
    int* bucketbase  = (int*)(w + off); off += align256(513 * 4);
    int* gcur        = (int*)(w + off); off += align256(512 * 4);
    int* flag64      = (int*)(w + off); off += align256(256);
    unsigned* stg    = (unsigned*)(w + off); off += align256((size_t)E * 4);
    int* ed          = (int*)(w + off); off += align256((size_t)E * 4 + 64);
    __hip_bfloat16* hwA = (__hip_bfloat16*)(w + off); off += align256((size_t)n * H * 2);
    __hip_bfloat16* hwB = (__hip_bfloat16*)(w + off); off += align256((size_t)n * H * 2);
    float* jk        = (float*)(w + off); off += align256((size_t)n * H * 4);

    int NB = (n + 255) / 256;          // 391 buckets of 256 nodes

    hipMemsetAsync(bucketcnt, 0, 512 * 4, stream);
    detect_kernel<<<1, 256, 0, stream>>>((const int*)eidx, flag64);
    bcount_kernel<<<512, 256, 0, stream>>>(eidx, E, flag64, n, bucketcnt);
    bscan_kernel<<<1, 512, 0, stream>>>(bucketcnt, NB, E, gcur, bucketbase);
    int SG = (E + 4095) / 4096;        // chunk <= 4096 <= SCH
    stage_kernel<<<SG, 256, 0, stream>>>(eidx, E, flag64, n, gcur, stg);
    fine_kernel<<<NB, 256, 0, stream>>>(stg, bucketbase, n, E, ed, rowstart, dinv);

    int ngrid = (n + NPB - 1) / NPB;   // 6250
    t0_kernel<<<ngrid, 256, 0, stream>>>(x, W0, dinv, hwA, n);

    __hip_bfloat16* cur = hwA;
    __hip_bfloat16* nxt = hwB;
    int agrid = (n + 63) / 64;         // 1563
    for (int l = 0; l < L; ++l) {
        const float* bias  = bs + (size_t)l * H;
        const float* Wnext = (l < L - 1) ? (Ws + (size_t)l * H * H) : nullptr;
        agg_kernel<<<agrid, 256, 0, stream>>>(ed, rowstart, dinv, cur, bias, Wnext,
                                              jk, nxt, fc_w, fc_b, (float*)d_out,
                                              n, (l == 0) ? 1 : 0,
                                              (l < L - 1) ? 1 : 0,
                                              (l == L - 1) ? 1 : 0);
        __hip_bfloat16* t = cur; cur = nxt; nxt = t;
    }
}